// Round 5
// baseline (164.277 us; speedup 1.0000x reference)
//
#include <hip/hip_runtime.h>

// Problem constants: B=256, T=256, H=768, S=130
#define BB 256
#define TT 256
#define HH 768
#define SS 130
#define SP 144   // S padded to 9 n-tiles of 16

typedef __attribute__((ext_vector_type(8))) __bf16 bf16x8;
typedef __attribute__((ext_vector_type(4))) float f32x4;

__device__ __forceinline__ unsigned f2bf(float f) {
    unsigned x = __builtin_bit_cast(unsigned, f);
    x = (x + 0x7FFFu + ((x >> 16) & 1u)) >> 16;
    return x & 0xFFFFu;
}

__device__ __forceinline__ bf16x8 pack8(const float4& a, const float4& b) {
    union { bf16x8 v; unsigned u[4]; } r;
    r.u[0] = f2bf(a.x) | (f2bf(a.y) << 16);
    r.u[1] = f2bf(a.z) | (f2bf(a.w) << 16);
    r.u[2] = f2bf(b.x) | (f2bf(b.y) << 16);
    r.u[3] = f2bf(b.z) | (f2bf(b.w) << 16);
    return r.v;
}

// ---- K0: W [768][130] f32 -> wsT [144][768] bf16 (transposed; pad rows zeroed) ----
__global__ __launch_bounds__(256)
void conv_w_kernel(const float* __restrict__ W, unsigned short* __restrict__ wsT)
{
    int idx = blockIdx.x * 256 + threadIdx.x;   // over 144*768/2 bf16-pairs
    if (idx >= SP * HH / 2) return;
    int s  = idx / (HH / 2);
    int kp = idx % (HH / 2);
    unsigned u = 0;
    if (s < SS) {
        u = f2bf(W[(size_t)(2 * kp) * SS + s]) |
            (f2bf(W[(size_t)(2 * kp + 1) * SS + s]) << 16);
    }
    *(unsigned*)(wsT + (size_t)s * HH + 2 * kp) = u;
}

// ---- K1: barrier-free GEMM, depth-9 B staircase, B-before-A issue order ----
// logits[b][s][t] = hidden[b][1+t][:] . W[:][s] + bias[s]
__global__ __launch_bounds__(256, 3)
void gemm_kernel(const float* __restrict__ hidden,
                 const unsigned short* __restrict__ wsT,
                 const float* __restrict__ bias,
                 float* __restrict__ logits)
{
    const int tid  = threadIdx.x;
    const int wv   = tid >> 6;
    const int lane = tid & 63;
    const int b    = blockIdx.x >> 2;
    const int tb   = (blockIdx.x & 3) << 6;          // 64-token span per block

    const int row16 = lane & 15;
    const int kq    = (lane >> 4) * 8;               // lane's k-offset within a 32-step

    const float* Abase = hidden + (size_t)b * (TT + 1) * HH
                       + (size_t)(1 + tb + wv * 16 + row16) * HH + kq;
    const unsigned short* Bb = wsT + (size_t)row16 * HH + kq;

    f32x4 acc[9];
    #pragma unroll
    for (int j = 0; j < 9; ++j) acc[j] = (f32x4){0.f, 0.f, 0.f, 0.f};

    // prologue A prefetch (k = 0)
    float4 pa0 = *(const float4*)(Abase);
    float4 pa1 = *(const float4*)(Abase + 4);

    for (int i = 0; i < 24; ++i) {
        const int k0 = i * 32;

        // consume current A regs into the MFMA A-fragment (VALU, no memory)
        bf16x8 af = pack8(pa0, pa1);

        // 1) issue ALL 9 B loads first (L2-fast; oldest in vmcnt queue)
        bf16x8 bfr[9];
        #pragma unroll
        for (int nt = 0; nt < 9; ++nt)
            bfr[nt] = *(const bf16x8*)(Bb + (size_t)nt * 16 * HH + k0);

        // 2) THEN issue next-step A prefetch (HBM-slow; newest -> does not
        //    block B retirement under in-order vmcnt)
        const int kn = (i < 23) ? (k0 + 32) : (HH - 64);   // uniform clamp, no branch
        pa0 = *(const float4*)(Abase + kn);
        pa1 = *(const float4*)(Abase + kn + 4);

        // pin: no load may sink below this point, no MFMA may hoist above
        __builtin_amdgcn_sched_barrier(0);

        #pragma unroll
        for (int nt = 0; nt < 9; ++nt)
            acc[nt] = __builtin_amdgcn_mfma_f32_16x16x32_bf16(af, bfr[nt], acc[nt], 0, 0, 0);
    }

    // epilogue: +bias, store [b][s][t] with t-contiguous float4 per lane
    const int tq = tb + wv * 16 + (lane >> 4) * 4;   // D row = (lane>>4)*4 + r
    #pragma unroll
    for (int nt = 0; nt < 9; ++nt) {
        int s = nt * 16 + row16;                      // D col = lane&15
        if (s < SS) {
            float bs = bias[s];
            float4 v = make_float4(acc[nt][0] + bs, acc[nt][1] + bs,
                                   acc[nt][2] + bs, acc[nt][3] + bs);
            *(float4*)(logits + ((size_t)b * SS + s) * TT + tq) = v;
        }
    }
}

// ---- K2: ragged segment-mean along t; one block per (s, b); high occupancy ----
__global__ __launch_bounds__(256)
void merge_kernel(const int* __restrict__ seg,
                  const float* __restrict__ logits,
                  float* __restrict__ out)
{
    __shared__ int   segl[TT];
    __shared__ int   startw[TT];
    __shared__ int   cntw[TT];
    __shared__ float row[TT];

    const int s   = blockIdx.x;
    const int b   = blockIdx.y;
    const int tid = threadIdx.x;

    segl[tid] = seg[b * TT + tid];
    cntw[tid] = 0;
    row[tid]  = logits[((size_t)b * SS + s) * TT + tid];
    __syncthreads();

    int id = segl[tid];
    if (tid == 0 || segl[tid - 1] != id) {    // run starts (seg row-sorted)
        int e = tid;
        while (e + 1 < TT && segl[e + 1] == id) ++e;
        startw[id] = tid;
        cntw[id]   = e - tid + 1;
    }
    __syncthreads();

    const int cn = cntw[tid];
    const int st = (cn > 0) ? startw[tid] : 0;
    float a = 0.f;
    for (int k = 0; k < cn; ++k) a += row[st + k];
    out[((size_t)b * SS + s) * TT + tid] = (cn > 0) ? a / (float)cn : 0.f;
}

extern "C" void kernel_launch(void* const* d_in, const int* in_sizes, int n_in,
                              void* d_out, int out_size, void* d_ws, size_t ws_size,
                              hipStream_t stream)
{
    const float* hidden = (const float*)d_in[0];  // [256, 257, 768] f32
    const float* W      = (const float*)d_in[1];  // [768, 130] f32
    const float* bias   = (const float*)d_in[2];  // [130] f32
    const int*   seg    = (const int*)d_in[3];    // [256, 256] i32 (row-sorted)
    float* out = (float*)d_out;                   // [256, 130, 256] f32

    unsigned short* wsT = (unsigned short*)d_ws;              // 221184 B
    float* logits = (float*)((char*)d_ws + 221184);           // [256][130][256] f32 = 34 MB

    (void)in_sizes; (void)n_in; (void)ws_size; (void)out_size;

    conv_w_kernel<<<dim3(SP * HH / 2 / 256), dim3(256), 0, stream>>>(W, wsT);
    gemm_kernel<<<dim3(BB * 4), dim3(256), 0, stream>>>(hidden, wsT, bias, logits);
    merge_kernel<<<dim3(SS, BB), dim3(256), 0, stream>>>(seg, logits, out);
}

// Round 6
// 151.507 us; speedup vs baseline: 1.0843x; 1.0843x over previous
//
#include <hip/hip_runtime.h>

// Problem constants: B=256, T=256, H=768, S=130
#define BB 256
#define TT 256
#define HH 768
#define SS 130
#define SP 144     // S padded to 9 n-tiles of 16
#define KC 64      // K-chunk (floats) per staging step; 12 chunks
#define NCH (HH / KC)
#define AS 72      // A_lds row stride in ushorts (64 + 8 pad)
#define BS 72      // B_lds row stride in ushorts

typedef __attribute__((ext_vector_type(8))) __bf16 bf16x8;
typedef __attribute__((ext_vector_type(4))) float f32x4;

__device__ __forceinline__ unsigned f2bf(float f) {
    unsigned x = __builtin_bit_cast(unsigned, f);
    x = (x + 0x7FFFu + ((x >> 16) & 1u)) >> 16;
    return x & 0xFFFFu;
}

// ---- K0: W [768][130] f32 -> wsT2 [12][144][64] bf16 (k-chunk-major tiles) ----
__global__ __launch_bounds__(256)
void conv_w_kernel(const float* __restrict__ W, unsigned* __restrict__ wsT2)
{
    int idx = blockIdx.x * 256 + threadIdx.x;      // over 12*144*32 uints
    if (idx >= NCH * SP * 32) return;
    int kc = idx / (SP * 32);
    int r  = idx % (SP * 32);
    int s  = r / 32;
    int kp = r % 32;
    int k  = kc * KC + 2 * kp;
    unsigned u = 0;
    if (s < SS) {
        u = f2bf(W[(size_t)k * SS + s]) |
            (f2bf(W[(size_t)(k + 1) * SS + s]) << 16);
    }
    wsT2[idx] = u;   // contiguous writes
}

// ---- K1: LDS-staged GEMM, 64-token tile, 4 waves, 4 blocks/CU ----
// logits[b][s][t] = hidden[b][1+t][:] . W[:][s] + bias[s]
__global__ __launch_bounds__(256, 4)
void gemm_kernel(const float* __restrict__ hidden,
                 const unsigned short* __restrict__ wsT2,
                 const float* __restrict__ bias,
                 float* __restrict__ logits)
{
    __shared__ __align__(16) unsigned short A_us[64 * AS];   //  9216 B
    __shared__ __align__(16) unsigned short B_us[SP * BS];   // 20736 B

    const int tid  = threadIdx.x;
    const int wv   = tid >> 6;
    const int lane = tid & 63;
    const int b    = blockIdx.x >> 2;
    const int tb   = (blockIdx.x & 3) << 6;        // 64-token span

    const float* Arow = hidden + (size_t)b * (TT + 1) * HH + HH + (size_t)tb * HH;

    const int fq = tid & 15;        // float4 index within 64-float chunk
    const int tr = tid >> 4;        // base row 0..15 (+16j)

    f32x4 acc[9];
    #pragma unroll
    for (int j = 0; j < 9; ++j) acc[j] = (f32x4){0.f, 0.f, 0.f, 0.f};

    float4 pa[4];    // A prefetch: rows tr+16j, 16B each (4-seg wave pattern)
    uint4  pb[5];    // B prefetch: contiguous uint4 stream from wsT2 tile

    // prologue: chunk 0 loads
    #pragma unroll
    for (int j = 0; j < 4; ++j)
        pa[j] = *(const float4*)(Arow + (size_t)(tr + 16 * j) * HH + fq * 4);
    #pragma unroll
    for (int i = 0; i < 5; ++i) {
        int c = tid + 256 * i;
        if (c < SP * 8)
            pb[i] = *(const uint4*)(wsT2 + c * 8);
    }

    for (int kc = 0; kc < NCH; ++kc) {
        // stage A (convert f32->bf16) and B (raw copy) from prefetch regs
        #pragma unroll
        for (int j = 0; j < 4; ++j) {
            int t = tr + 16 * j;
            unsigned lo = f2bf(pa[j].x) | (f2bf(pa[j].y) << 16);
            unsigned hi = f2bf(pa[j].z) | (f2bf(pa[j].w) << 16);
            *(uint2*)(A_us + t * AS + fq * 4) = make_uint2(lo, hi);
        }
        #pragma unroll
        for (int i = 0; i < 5; ++i) {
            int c = tid + 256 * i;
            if (c < SP * 8)
                *(uint4*)(B_us + (c >> 3) * BS + (c & 7) * 8) = pb[i];
        }
        __syncthreads();

        // issue next chunk's global loads before MFMA (latency hides under
        // this block's MFMA + other resident blocks' work)
        if (kc + 1 < NCH) {
            const int kn = (kc + 1) * KC;
            #pragma unroll
            for (int j = 0; j < 4; ++j)
                pa[j] = *(const float4*)(Arow + (size_t)(tr + 16 * j) * HH + kn + fq * 4);
            const unsigned short* Bt = wsT2 + (size_t)(kc + 1) * SP * KC;
            #pragma unroll
            for (int i = 0; i < 5; ++i) {
                int c = tid + 256 * i;
                if (c < SP * 8)
                    pb[i] = *(const uint4*)(Bt + c * 8);
            }
        }

        // MFMA: 2 k-steps of 32, 9 n-tiles; wave owns 16 tokens
        #pragma unroll
        for (int ks = 0; ks < 2; ++ks) {
            const int kof = ks * 32 + (lane >> 4) * 8;
            bf16x8 af = *(const bf16x8*)(A_us + (wv * 16 + (lane & 15)) * AS + kof);
            #pragma unroll
            for (int nt = 0; nt < 9; ++nt) {
                bf16x8 bfr = *(const bf16x8*)(B_us + (nt * 16 + (lane & 15)) * BS + kof);
                acc[nt] = __builtin_amdgcn_mfma_f32_16x16x32_bf16(af, bfr, acc[nt], 0, 0, 0);
            }
        }
        __syncthreads();
    }

    // epilogue: +bias, store [b][s][t], t-contiguous float4 per lane
    const int tq = tb + wv * 16 + (lane >> 4) * 4;   // D row = (lane>>4)*4 + r
    #pragma unroll
    for (int nt = 0; nt < 9; ++nt) {
        int s = nt * 16 + (lane & 15);               // D col = lane&15
        if (s < SS) {
            float bs = bias[s];
            float4 v = make_float4(acc[nt][0] + bs, acc[nt][1] + bs,
                                   acc[nt][2] + bs, acc[nt][3] + bs);
            *(float4*)(logits + ((size_t)b * SS + s) * TT + tq) = v;
        }
    }
}

// ---- K2: ragged segment-mean along t; one block per (s, b) ----
__global__ __launch_bounds__(256)
void merge_kernel(const int* __restrict__ seg,
                  const float* __restrict__ logits,
                  float* __restrict__ out)
{
    __shared__ int   segl[TT];
    __shared__ int   startw[TT];
    __shared__ int   cntw[TT];
    __shared__ float row[TT];

    const int s   = blockIdx.x;
    const int b   = blockIdx.y;
    const int tid = threadIdx.x;

    segl[tid] = seg[b * TT + tid];
    cntw[tid] = 0;
    row[tid]  = logits[((size_t)b * SS + s) * TT + tid];
    __syncthreads();

    int id = segl[tid];
    if (tid == 0 || segl[tid - 1] != id) {    // run starts (seg row-sorted)
        int e = tid;
        while (e + 1 < TT && segl[e + 1] == id) ++e;
        startw[id] = tid;
        cntw[id]   = e - tid + 1;
    }
    __syncthreads();

    const int cn = cntw[tid];
    const int st = (cn > 0) ? startw[tid] : 0;
    float a = 0.f;
    for (int k = 0; k < cn; ++k) a += row[st + k];
    out[((size_t)b * SS + s) * TT + tid] = (cn > 0) ? a / (float)cn : 0.f;
}

extern "C" void kernel_launch(void* const* d_in, const int* in_sizes, int n_in,
                              void* d_out, int out_size, void* d_ws, size_t ws_size,
                              hipStream_t stream)
{
    const float* hidden = (const float*)d_in[0];  // [256, 257, 768] f32
    const float* W      = (const float*)d_in[1];  // [768, 130] f32
    const float* bias   = (const float*)d_in[2];  // [130] f32
    const int*   seg    = (const int*)d_in[3];    // [256, 256] i32 (row-sorted)
    float* out = (float*)d_out;                   // [256, 130, 256] f32

    unsigned* wsT2 = (unsigned*)d_ws;                         // 221184 B
    float* logits  = (float*)((char*)d_ws + 221184);          // [256][130][256] f32

    (void)in_sizes; (void)n_in; (void)ws_size; (void)out_size;

    conv_w_kernel<<<dim3(NCH * SP * 32 / 256), dim3(256), 0, stream>>>(W, wsT2);
    gemm_kernel<<<dim3(BB * 4), dim3(256), 0, stream>>>(hidden, (const unsigned short*)wsT2, bias, logits);
    merge_kernel<<<dim3(SS, BB), dim3(256), 0, stream>>>(seg, logits, out);
}

// Round 7
// 113.896 us; speedup vs baseline: 1.4423x; 1.3302x over previous
//
#include <hip/hip_runtime.h>

// Problem constants: B=256, T=256, H=768, S=130
#define BB 256
#define TT 256
#define HH 768
#define SS 130
#define SPAD 160                 // padded S rows per B k-chunk tile (DMA-uniform: 5 x 1024B per wave)
#define NCH 12                   // 768 / 64
#define CHB (SPAD * 128)         // bytes per B chunk tile = 20480

typedef __attribute__((ext_vector_type(8))) __bf16 bf16x8;
typedef __attribute__((ext_vector_type(4))) float f32x4;

__device__ __forceinline__ unsigned f2bf(float f) {
    unsigned x = __builtin_bit_cast(unsigned, f);
    x = (x + 0x7FFFu + ((x >> 16) & 1u)) >> 16;
    return x & 0xFFFFu;
}

// ---- K0: W [768][130] f32 -> wsT2 [12][160][64] bf16 k-chunk tiles, with the
// ds_read XOR-swizzle PRE-BAKED into the source layout (T2 + m173: linear DMA
// dest + pre-swizzled source == swizzled LDS). 16B chunk j of row s lands at
// byte s*128 + (j ^ (s&7))*16 within its tile.
__global__ __launch_bounds__(256)
void conv_w_kernel(const float* __restrict__ W, unsigned* __restrict__ wsT2)
{
    int idx = blockIdx.x * 256 + threadIdx.x;   // logical uints: 12*160*32 = 61440
    if (idx >= NCH * SPAD * 32) return;
    int kc = idx / (SPAD * 32);
    int r  = idx % (SPAD * 32);
    int s  = r >> 5;
    int q  = r & 31;                            // logical uint (bf16-pair) within row
    unsigned u = 0;
    if (s < SS) {
        int k = kc * 64 + 2 * q;
        u = f2bf(W[(size_t)k * SS + s]) | (f2bf(W[(size_t)(k + 1) * SS + s]) << 16);
    }
    int phys = kc * (SPAD * 32) + (s << 5) + ((((q >> 2) ^ (s & 7)) << 2) | (q & 3));
    wsT2[phys] = u;
}

// ---- K1: GEMM. B: global_load_lds double-buffer + counted vmcnt + 1 raw
// barrier/chunk. A: direct global->register fragments, depth-2 prefetch,
// v_cvt_pk_bf16_f32 conversion. No ds_write, no __syncthreads, no spills. ----
__global__ __launch_bounds__(256, 4)
void gemm_kernel(const float* __restrict__ hidden,
                 const char* __restrict__ wsT2,
                 const float* __restrict__ bias,
                 float* __restrict__ logits)
{
    __shared__ __align__(16) unsigned Blds_u[2 * CHB / 4];   // 40960 B

    const int tid  = threadIdx.x;
    const int wv   = tid >> 6;
    const int lane = tid & 63;
    const int r16  = lane & 15;
    const int g    = lane >> 4;                 // 0..3
    const int b    = blockIdx.x >> 2;
    const int tb   = (blockIdx.x & 3) << 6;     // 64-token span

    // A fragment source: row = own token, k-offset g*8 within each 32-step
    const float* Abase = hidden + (size_t)b * (TT + 1) * HH
                       + (size_t)(1 + tb + wv * 16 + r16) * HH + g * 8;

    f32x4 acc[9];
    #pragma unroll
    for (int j = 0; j < 9; ++j) acc[j] = (f32x4){0.f, 0.f, 0.f, 0.f};

    // swizzled B fragment offsets: chunk j_log = ks*4+g, read at (j_log ^ (r16&7))*16
    const int xv = g ^ (r16 & 7);
    const int x0 = xv << 4;
    const int x1 = (xv ^ 4) << 4;

    // ---- prologue: B_0 DMA, then A_0, A_1 register prefetch ----
    {
        const char* gsrc = wsT2 + (size_t)wv * 5120 + (size_t)lane * 16;
        unsigned* ldst = Blds_u + (wv * 5120) / 4;
        #pragma unroll
        for (int i = 0; i < 5; ++i)
            __builtin_amdgcn_global_load_lds((const unsigned*)(gsrc + i * 1024),
                                             ldst + i * 256, 16, 0, 0);
    }
    float4 paA[4], paB[4];
    paA[0] = *(const float4*)(Abase);       paA[1] = *(const float4*)(Abase + 4);
    paA[2] = *(const float4*)(Abase + 32);  paA[3] = *(const float4*)(Abase + 36);
    paB[0] = *(const float4*)(Abase + 64);  paB[1] = *(const float4*)(Abase + 68);
    paB[2] = *(const float4*)(Abase + 96);  paB[3] = *(const float4*)(Abase + 100);

    auto chunk = [&](float4 (&pa)[4], const int kc, const int par) {
        // convert A_kc -> two fragments (compiler inserts the counted vmcnt for pa)
        union { unsigned u[4]; bf16x8 v; } af0u, af1u;
        asm("v_cvt_pk_bf16_f32 %0, %1, %2" : "=v"(af0u.u[0]) : "v"(pa[0].x), "v"(pa[0].y));
        asm("v_cvt_pk_bf16_f32 %0, %1, %2" : "=v"(af0u.u[1]) : "v"(pa[0].z), "v"(pa[0].w));
        asm("v_cvt_pk_bf16_f32 %0, %1, %2" : "=v"(af0u.u[2]) : "v"(pa[1].x), "v"(pa[1].y));
        asm("v_cvt_pk_bf16_f32 %0, %1, %2" : "=v"(af0u.u[3]) : "v"(pa[1].z), "v"(pa[1].w));
        asm("v_cvt_pk_bf16_f32 %0, %1, %2" : "=v"(af1u.u[0]) : "v"(pa[2].x), "v"(pa[2].y));
        asm("v_cvt_pk_bf16_f32 %0, %1, %2" : "=v"(af1u.u[1]) : "v"(pa[2].z), "v"(pa[2].w));
        asm("v_cvt_pk_bf16_f32 %0, %1, %2" : "=v"(af1u.u[2]) : "v"(pa[3].x), "v"(pa[3].y));
        asm("v_cvt_pk_bf16_f32 %0, %1, %2" : "=v"(af1u.u[3]) : "v"(pa[3].z), "v"(pa[3].w));

        // B_kc DMA complete (own 5 instrs), keep A_{kc+1} (4 instrs) in flight
        asm volatile("s_waitcnt vmcnt(4)" ::: "memory");
        __builtin_amdgcn_s_barrier();
        __builtin_amdgcn_sched_barrier(0);

        // issue B_{kc+1} DMA into the other buffer (safe: all waves passed the
        // barrier, so nobody still reads buffer (1-par) from chunk kc-1)
        {
            const int kb = (kc + 1 < NCH) ? kc + 1 : NCH - 1;
            const char* gsrc = wsT2 + (size_t)kb * CHB + (size_t)wv * 5120 + (size_t)lane * 16;
            unsigned* ldst = Blds_u + ((1 - par) * CHB + wv * 5120) / 4;
            #pragma unroll
            for (int i = 0; i < 5; ++i)
                __builtin_amdgcn_global_load_lds((const unsigned*)(gsrc + i * 1024),
                                                 ldst + i * 256, 16, 0, 0);
        }
        // issue A_{kc+2} into the just-freed registers
        {
            const int ka = (kc + 2 < NCH) ? kc + 2 : NCH - 1;
            const float* ap = Abase + ka * 64;
            pa[0] = *(const float4*)(ap);       pa[1] = *(const float4*)(ap + 4);
            pa[2] = *(const float4*)(ap + 32);  pa[3] = *(const float4*)(ap + 36);
        }

        // MFMA phase: 18 swizzled ds_read_b128 + 18 MFMA (compiler handles lgkmcnt)
        const char* base = (const char*)Blds_u + par * CHB + r16 * 128;
        #pragma unroll
        for (int nt = 0; nt < 9; ++nt)
            acc[nt] = __builtin_amdgcn_mfma_f32_16x16x32_bf16(
                af0u.v, *(const bf16x8*)(base + nt * 2048 + x0), acc[nt], 0, 0, 0);
        #pragma unroll
        for (int nt = 0; nt < 9; ++nt)
            acc[nt] = __builtin_amdgcn_mfma_f32_16x16x32_bf16(
                af1u.v, *(const bf16x8*)(base + nt * 2048 + x1), acc[nt], 0, 0, 0);
    };

    #pragma unroll 1
    for (int kp = 0; kp < NCH / 2; ++kp) {
        chunk(paA, 2 * kp, 0);
        chunk(paB, 2 * kp + 1, 1);
    }

    // drain tail loads (clamped A_{12,13}, B_12 DMA) before ending
    asm volatile("s_waitcnt vmcnt(0)" ::: "memory");

    // epilogue: +bias, store [b][s][t] with t-contiguous float4 per lane
    const int tq = tb + wv * 16 + g * 4;         // D row = g*4 + i
    #pragma unroll
    for (int nt = 0; nt < 9; ++nt) {
        int s = nt * 16 + r16;                    // D col = r16
        if (s < SS) {
            float bs = bias[s];
            float4 v = make_float4(acc[nt][0] + bs, acc[nt][1] + bs,
                                   acc[nt][2] + bs, acc[nt][3] + bs);
            *(float4*)(logits + ((size_t)b * SS + s) * TT + tq) = v;
        }
    }
}

// ---- K2: ragged segment-mean along t; one block per (s, b) ----
__global__ __launch_bounds__(256)
void merge_kernel(const int* __restrict__ seg,
                  const float* __restrict__ logits,
                  float* __restrict__ out)
{
    __shared__ int   segl[TT];
    __shared__ int   startw[TT];
    __shared__ int   cntw[TT];
    __shared__ float row[TT];

    const int s   = blockIdx.x;
    const int b   = blockIdx.y;
    const int tid = threadIdx.x;

    segl[tid] = seg[b * TT + tid];
    cntw[tid] = 0;
    row[tid]  = logits[((size_t)b * SS + s) * TT + tid];
    __syncthreads();

    int id = segl[tid];
    if (tid == 0 || segl[tid - 1] != id) {    // run starts (seg row-sorted)
        int e = tid;
        while (e + 1 < TT && segl[e + 1] == id) ++e;
        startw[id] = tid;
        cntw[id]   = e - tid + 1;
    }
    __syncthreads();

    const int cn = cntw[tid];
    const int st = (cn > 0) ? startw[tid] : 0;
    float a = 0.f;
    for (int k = 0; k < cn; ++k) a += row[st + k];
    out[((size_t)b * SS + s) * TT + tid] = (cn > 0) ? a / (float)cn : 0.f;
}

extern "C" void kernel_launch(void* const* d_in, const int* in_sizes, int n_in,
                              void* d_out, int out_size, void* d_ws, size_t ws_size,
                              hipStream_t stream)
{
    const float* hidden = (const float*)d_in[0];  // [256, 257, 768] f32
    const float* W      = (const float*)d_in[1];  // [768, 130] f32
    const float* bias   = (const float*)d_in[2];  // [130] f32
    const int*   seg    = (const int*)d_in[3];    // [256, 256] i32 (row-sorted)
    float* out = (float*)d_out;                   // [256, 130, 256] f32

    unsigned* wsT2 = (unsigned*)d_ws;                       // 12*20480 = 245760 B
    float* logits  = (float*)((char*)d_ws + NCH * CHB);     // [256][130][256] f32

    (void)in_sizes; (void)n_in; (void)ws_size; (void)out_size;

    conv_w_kernel<<<dim3(NCH * SPAD * 32 / 256), dim3(256), 0, stream>>>(W, wsT2);
    gemm_kernel<<<dim3(BB * 4), dim3(256), 0, stream>>>(hidden, (const char*)wsT2, bias, logits);
    merge_kernel<<<dim3(SS, BB), dim3(256), 0, stream>>>(seg, logits, out);
}

// Round 8
// 89.766 us; speedup vs baseline: 1.8300x; 1.2688x over previous
//
#include <hip/hip_runtime.h>

// Problem constants: B=256, T=256, H=768, S=130
#define BB 256
#define TT 256
#define HH 768
#define SS 130
#define SPAD 160                 // padded S rows per B k-chunk tile
#define NCH 12                   // 768 / 64
#define CHB (SPAD * 128)         // bytes per B chunk tile = 20480

typedef __attribute__((ext_vector_type(8))) __bf16 bf16x8;
typedef __attribute__((ext_vector_type(4))) float f32x4;

__device__ __forceinline__ unsigned f2bf(float f) {
    unsigned x = __builtin_bit_cast(unsigned, f);
    x = (x + 0x7FFFu + ((x >> 16) & 1u)) >> 16;
    return x & 0xFFFFu;
}

// ---- K0: W [768][130] f32 -> wsT2 [12][160 s][64 k] bf16 tiles, XOR-swizzle
// pre-baked (16B chunk j of row s lands at byte s*128 + (j^(s&7))*16).
// Coalesced: LDS-transpose per 64-k chunk, 12 blocks.
__global__ __launch_bounds__(256)
void conv_w_kernel(const float* __restrict__ W, unsigned* __restrict__ wsT2)
{
    __shared__ float Wl[64 * 132];           // 64 k-rows x 130 s (pad 132)
    const int kc  = blockIdx.x;
    const int tid = threadIdx.x;

    const float* src = W + (size_t)kc * 64 * SS;
    for (int i = tid; i < 64 * SS; i += 256) {      // coalesced load
        int r = i / SS, c = i - r * SS;
        Wl[r * 132 + c] = src[i];
    }
    __syncthreads();

    for (int u = tid; u < SPAD * 32; u += 256) {    // coalesced swizzled write
        int s  = u >> 5;
        int qp = u & 31;                             // physical uint slot in row
        int q  = ((((qp >> 2) ^ (s & 7)) << 2) | (qp & 3));  // logical k-pair (XOR involution)
        unsigned v = 0;
        if (s < SS) {
            v = f2bf(Wl[(2 * q) * 132 + s]) | (f2bf(Wl[(2 * q + 1) * 132 + s]) << 16);
        }
        wsT2[kc * (SPAD * 32) + u] = v;
    }
}

// ---- Kseg: per-row run boundaries (seg row-sorted): bounds[b][w] = {start,count} ----
__global__ __launch_bounds__(256)
void seg_kernel(const int* __restrict__ seg, int2* __restrict__ bounds)
{
    __shared__ int segl[TT];
    __shared__ int st_s[TT];
    __shared__ int cn_s[TT];
    const int b   = blockIdx.x;
    const int tid = threadIdx.x;

    segl[tid] = seg[b * TT + tid];
    st_s[tid] = 0;
    cn_s[tid] = 0;
    __syncthreads();

    int id = segl[tid];
    if (tid == 0 || segl[tid - 1] != id) {
        int e = tid;
        while (e + 1 < TT && segl[e + 1] == id) ++e;
        st_s[id] = tid;
        cn_s[id] = e - tid + 1;
    }
    __syncthreads();

    bounds[b * TT + tid] = make_int2(st_s[tid], cn_s[tid]);
}

// ---- K1: GEMM. B: global_load_lds dbuf + vmcnt(4) + 1 barrier/chunk.
// A: direct global->fragment, depth-2 prefetch in NAMED registers (no arrays,
// no lambda -> nothing for the allocator to spill). ----
__global__ __launch_bounds__(256, 4)
void gemm_kernel(const float* __restrict__ hidden,
                 const char* __restrict__ wsT2,
                 const float* __restrict__ bias,
                 float* __restrict__ logits)
{
    __shared__ __align__(16) char Blds[2 * CHB];   // 40960 B -> 4 blocks/CU exactly

    const int tid  = threadIdx.x;
    const int wv   = tid >> 6;
    const int lane = tid & 63;
    const int r16  = lane & 15;
    const int g    = lane >> 4;
    const int b    = blockIdx.x >> 2;
    const int tb   = (blockIdx.x & 3) << 6;

    const float* Abase = hidden + (size_t)b * (TT + 1) * HH
                       + (size_t)(1 + tb + wv * 16 + r16) * HH + g * 8;

    f32x4 acc[9];
    #pragma unroll
    for (int j = 0; j < 9; ++j) acc[j] = (f32x4){0.f, 0.f, 0.f, 0.f};

    const int xv = g ^ (r16 & 7);
    const int x0 = xv << 4;
    const int x1 = (xv ^ 4) << 4;

    // prologue: B_0 DMA + A_0, A_1 register prefetch
    {
        const char* gs = wsT2 + (size_t)wv * 5120 + (size_t)lane * 16;
        unsigned* ld_ = (unsigned*)(Blds + wv * 5120);
        #pragma unroll
        for (int i = 0; i < 5; ++i)
            __builtin_amdgcn_global_load_lds((const unsigned*)(gs + i * 1024),
                                             ld_ + i * 256, 16, 0, 0);
    }
    float4 a00, a01, a02, a03, a10, a11, a12, a13;
    a00 = *(const float4*)(Abase);       a01 = *(const float4*)(Abase + 4);
    a02 = *(const float4*)(Abase + 32);  a03 = *(const float4*)(Abase + 36);
    a10 = *(const float4*)(Abase + 64);  a11 = *(const float4*)(Abase + 68);
    a12 = *(const float4*)(Abase + 96);  a13 = *(const float4*)(Abase + 100);

#define CHUNK(A0, A1, A2, A3, KC_, PAR)                                                  \
    do {                                                                                  \
        union { unsigned u[4]; bf16x8 v; } af0u, af1u;                                    \
        asm("v_cvt_pk_bf16_f32 %0, %1, %2" : "=v"(af0u.u[0]) : "v"(A0.x), "v"(A0.y));     \
        asm("v_cvt_pk_bf16_f32 %0, %1, %2" : "=v"(af0u.u[1]) : "v"(A0.z), "v"(A0.w));     \
        asm("v_cvt_pk_bf16_f32 %0, %1, %2" : "=v"(af0u.u[2]) : "v"(A1.x), "v"(A1.y));     \
        asm("v_cvt_pk_bf16_f32 %0, %1, %2" : "=v"(af0u.u[3]) : "v"(A1.z), "v"(A1.w));     \
        asm("v_cvt_pk_bf16_f32 %0, %1, %2" : "=v"(af1u.u[0]) : "v"(A2.x), "v"(A2.y));     \
        asm("v_cvt_pk_bf16_f32 %0, %1, %2" : "=v"(af1u.u[1]) : "v"(A2.z), "v"(A2.w));     \
        asm("v_cvt_pk_bf16_f32 %0, %1, %2" : "=v"(af1u.u[2]) : "v"(A3.x), "v"(A3.y));     \
        asm("v_cvt_pk_bf16_f32 %0, %1, %2" : "=v"(af1u.u[3]) : "v"(A3.z), "v"(A3.w));     \
        asm volatile("s_waitcnt vmcnt(4)" ::: "memory");                                  \
        __builtin_amdgcn_s_barrier();                                                     \
        __builtin_amdgcn_sched_barrier(0);                                                \
        {                                                                                 \
            const int kb = ((KC_) + 1 < NCH) ? (KC_) + 1 : NCH - 1;                       \
            const char* gs = wsT2 + (size_t)kb * CHB + (size_t)wv * 5120 + (size_t)lane * 16; \
            unsigned* ld_ = (unsigned*)(Blds + (1 - (PAR)) * CHB + wv * 5120);            \
            _Pragma("unroll")                                                             \
            for (int i = 0; i < 5; ++i)                                                   \
                __builtin_amdgcn_global_load_lds((const unsigned*)(gs + i * 1024),        \
                                                 ld_ + i * 256, 16, 0, 0);                \
        }                                                                                 \
        {                                                                                 \
            const int ka = ((KC_) + 2 < NCH) ? (KC_) + 2 : NCH - 1;                       \
            const float* ap = Abase + ka * 64;                                            \
            A0 = *(const float4*)(ap);       A1 = *(const float4*)(ap + 4);               \
            A2 = *(const float4*)(ap + 32);  A3 = *(const float4*)(ap + 36);              \
        }                                                                                 \
        __builtin_amdgcn_sched_barrier(0);                                                \
        {                                                                                 \
            const char* base = Blds + (PAR) * CHB + r16 * 128;                            \
            _Pragma("unroll")                                                             \
            for (int nt = 0; nt < 9; ++nt)                                                \
                acc[nt] = __builtin_amdgcn_mfma_f32_16x16x32_bf16(                        \
                    af0u.v, *(const bf16x8*)(base + nt * 2048 + x0), acc[nt], 0, 0, 0);   \
            _Pragma("unroll")                                                             \
            for (int nt = 0; nt < 9; ++nt)                                                \
                acc[nt] = __builtin_amdgcn_mfma_f32_16x16x32_bf16(                        \
                    af1u.v, *(const bf16x8*)(base + nt * 2048 + x1), acc[nt], 0, 0, 0);   \
        }                                                                                 \
    } while (0)

    #pragma unroll 1
    for (int kp = 0; kp < NCH / 2; ++kp) {
        CHUNK(a00, a01, a02, a03, 2 * kp, 0);
        CHUNK(a10, a11, a12, a13, 2 * kp + 1, 1);
    }
#undef CHUNK

    asm volatile("s_waitcnt vmcnt(0)" ::: "memory");   // drain clamped tail loads

    // epilogue: +bias, store [b][s][t], t-contiguous float4 per lane
    const int tq = tb + wv * 16 + g * 4;               // D row = g*4 + i
    #pragma unroll
    for (int nt = 0; nt < 9; ++nt) {
        int s = nt * 16 + r16;                          // D col = r16
        if (s < SS) {
            float bs = bias[s];
            float4 v = make_float4(acc[nt][0] + bs, acc[nt][1] + bs,
                                   acc[nt][2] + bs, acc[nt][3] + bs);
            *(float4*)(logits + ((size_t)b * SS + s) * TT + tq) = v;
        }
    }
}

// ---- K2: barrier-free, LDS-free ragged segment-mean. block=(b, s-pair),
// thread = word w. logits row is L1-served; writes coalesced. ----
__global__ __launch_bounds__(256)
void merge_kernel(const int2* __restrict__ bounds,
                  const float* __restrict__ logits,
                  float* __restrict__ out)
{
    const int blk = blockIdx.x;          // 256 * 65
    const int b   = blk / 65;
    const int sp  = (blk - b * 65) * 2;
    const int w   = threadIdx.x;

    const int2 bc = bounds[b * TT + w];  // {start, count}
    const float inv = (bc.y > 0) ? 1.f / (float)bc.y : 0.f;

    #pragma unroll
    for (int i = 0; i < 2; ++i) {
        const int s = sp + i;            // 130 = 65*2, always valid
        const float* row = logits + ((size_t)b * SS + s) * TT;
        float a = 0.f;
        for (int k = 0; k < bc.y; ++k) a += row[bc.x + k];
        out[((size_t)b * SS + s) * TT + w] = a * inv;
    }
}

extern "C" void kernel_launch(void* const* d_in, const int* in_sizes, int n_in,
                              void* d_out, int out_size, void* d_ws, size_t ws_size,
                              hipStream_t stream)
{
    const float* hidden = (const float*)d_in[0];  // [256, 257, 768] f32
    const float* W      = (const float*)d_in[1];  // [768, 130] f32
    const float* bias   = (const float*)d_in[2];  // [130] f32
    const int*   seg    = (const int*)d_in[3];    // [256, 256] i32 (row-sorted)
    float* out = (float*)d_out;                   // [256, 130, 256] f32

    unsigned* wsT2 = (unsigned*)d_ws;                                  // 245760 B
    float*    logits = (float*)((char*)d_ws + NCH * CHB);              // 34078720 B
    int2*     bounds = (int2*)((char*)d_ws + NCH * CHB + (size_t)BB * SS * TT * 4);

    (void)in_sizes; (void)n_in; (void)ws_size; (void)out_size;

    conv_w_kernel<<<dim3(NCH), dim3(256), 0, stream>>>(W, wsT2);
    seg_kernel<<<dim3(BB), dim3(256), 0, stream>>>(seg, bounds);
    gemm_kernel<<<dim3(BB * 4), dim3(256), 0, stream>>>(hidden, (const char*)wsT2, bias, logits);
    merge_kernel<<<dim3(BB * (SS / 2)), dim3(256), 0, stream>>>(bounds, logits, out);
}